// Round 4
// baseline (106310.291 us; speedup 1.0000x reference)
//
#include <hip/hip_runtime.h>
#include <math.h>

#define B_  16
#define D_  2048
#define T_  100
#define N0_ 4096
#define N1_ 4096
#define N2_ 2048
#define NC_ 10
#define NBLK_ 256
#define NTHR_ 1024

struct Ptrs {
    float* Wa; float* Wb;
    const float* s0; const float* p0;
    const float* Wdec; const float* bdec;
    float* out;
    float* s1bj; float* s1r; float* q0bj; float* p1r;
    float* s2bk; float* q1bk;
    float* pa; float* pb;
    float* V1; float* r1; float* V2; float* r2;
    float* counts;
    unsigned* bar;   // bar[0]=cnt, bar[1]=gen
};

// ---------------- rates = sigmoid(x @ W_enc + b_enc) ----------------
__global__ __launch_bounds__(256) void rates_kernel(
    const float* __restrict__ x, const float* __restrict__ W_enc,
    const float* __restrict__ b_enc, float* __restrict__ rates)
{
    int tid = blockIdx.x * 256 + threadIdx.x;      // 65536 = B*N0
    int b = tid >> 12, i = tid & (N0_ - 1);
    const float* xr = x + b * D_;
    float acc = 0.f;
    for (int d = 0; d < D_; ++d)
        acc = fmaf(xr[d], W_enc[(size_t)d * N0_ + i], acc);
    float z = __fadd_rn(acc, b_enc[i]);
    rates[tid] = 1.0f / (1.0f + expf(-z));
}

// ---- layer-0 LIF over all T (weight-independent): s0, p0 in (T,N0,B) ----
__global__ __launch_bounds__(256) void layer0_kernel(
    const float* __restrict__ u, const float* __restrict__ rates,
    float* __restrict__ s0_all, float* __restrict__ p0_all)
{
    int tid = blockIdx.x * 256 + threadIdx.x;      // 65536
    int b = tid & (B_ - 1), i = tid >> 4;
    float rate = rates[b * N0_ + i];
    const float* ub = u + (size_t)b * T_ * N0_ + i;
    float V = 0.f, refr = 0.f, p0 = 0.f;
    for (int t = 0; t < T_; ++t) {
        float uv = ub[(size_t)t * N0_];
        float s_in = (uv < rate) ? 1.0f : 0.0f;
        V = __fadd_rn(__fmul_rn(0.9f, V), s_in);
        bool spk = (V > 1.0f) && (refr <= 0.0f);
        float s = spk ? 1.0f : 0.0f;
        V = spk ? 0.0f : V;
        refr = spk ? 2.0f : fmaxf(refr - 1.0f, 0.0f);
        p0 = __fadd_rn(__fmul_rn(0.95f, p0), s);
        size_t idx = ((size_t)t * N0_ + i) * B_ + b;
        s0_all[idx] = s;
        p0_all[idx] = p0;
    }
}

__device__ __forceinline__ float dot16q(float4 a0, float4 a1, float4 a2, float4 a3,
                                        const float* v) {
    float t = 0.f;
    t = fmaf(a0.x, v[0], t);  t = fmaf(a0.y, v[1], t);
    t = fmaf(a0.z, v[2], t);  t = fmaf(a0.w, v[3], t);
    t = fmaf(a1.x, v[4], t);  t = fmaf(a1.y, v[5], t);
    t = fmaf(a1.z, v[6], t);  t = fmaf(a1.w, v[7], t);
    t = fmaf(a2.x, v[8], t);  t = fmaf(a2.y, v[9], t);
    t = fmaf(a2.z, v[10], t); t = fmaf(a2.w, v[11], t);
    t = fmaf(a3.x, v[12], t); t = fmaf(a3.y, v[13], t);
    t = fmaf(a3.z, v[14], t); t = fmaf(a3.w, v[15], t);
    return t;
}
__device__ __forceinline__ void acc16q(float* acc, float4 a0, float4 a1, float4 a2,
                                       float4 a3, float w) {
    acc[0]  = fmaf(a0.x, w, acc[0]);  acc[1]  = fmaf(a0.y, w, acc[1]);
    acc[2]  = fmaf(a0.z, w, acc[2]);  acc[3]  = fmaf(a0.w, w, acc[3]);
    acc[4]  = fmaf(a1.x, w, acc[4]);  acc[5]  = fmaf(a1.y, w, acc[5]);
    acc[6]  = fmaf(a1.z, w, acc[6]);  acc[7]  = fmaf(a1.w, w, acc[7]);
    acc[8]  = fmaf(a2.x, w, acc[8]);  acc[9]  = fmaf(a2.y, w, acc[9]);
    acc[10] = fmaf(a2.z, w, acc[10]); acc[11] = fmaf(a2.w, w, acc[11]);
    acc[12] = fmaf(a3.x, w, acc[12]); acc[13] = fmaf(a3.y, w, acc[13]);
    acc[14] = fmaf(a3.z, w, acc[14]); acc[15] = fmaf(a3.w, w, acc[15]);
}

// Sense-reversing grid barrier. Safe: all 256 blocks are co-resident
// (256 blocks <= 256 CUs; VGPR use forces <=1 block/CU anyway).
__device__ __forceinline__ void gbar(unsigned* cnt, unsigned* gen, unsigned& mygen) {
    __threadfence();          // agent-scope release of this thread's stores
    __syncthreads();
    if (threadIdx.x == 0) {
        unsigned g = mygen;
        unsigned v = __hip_atomic_fetch_add(cnt, 1u, __ATOMIC_ACQ_REL,
                                            __HIP_MEMORY_SCOPE_AGENT);
        if (v == NBLK_ - 1u) {
            __hip_atomic_store(cnt, 0u, __ATOMIC_RELAXED, __HIP_MEMORY_SCOPE_AGENT);
            __hip_atomic_store(gen, g + 1u, __ATOMIC_RELEASE, __HIP_MEMORY_SCOPE_AGENT);
        } else {
            while (__hip_atomic_load(gen, __ATOMIC_ACQUIRE,
                                     __HIP_MEMORY_SCOPE_AGENT) <= g) {
                __builtin_amdgcn_s_sleep(1);
            }
        }
        mygen = g + 1u;
    }
    __syncthreads();
}

__global__ __launch_bounds__(NTHR_, 4) void snn_kernel(Ptrs p)
{
    __shared__ float trA[2 * 256 * 16];   // 32 KiB trace staging
    __shared__ float part2[16 * 256];     // 16 KiB in-block partial reduction
    const int tix = threadIdx.x;
    const int bx  = blockIdx.x;
    const int w = tix >> 6, lane = tix & 63;
    const int iq = w >> 2, jq = w & 3;
    unsigned mygen = 0;

    for (int t = 0; t < T_; ++t) {
        const int cur = t & 1, prv = 1 - cur;
        const int sw = (t < T_ - 1) ? 1 : 0;

        // ---- phase D(t-1): lif2, folded concurrent with phase A ----
        if (t > 0 && tix < 128) {
            int td = t - 1, dc = td & 1, dp = 1 - dc;
            int tgt = bx * 128 + tix;                  // 32768 = B*N2
            int b = tgt >> 11, k = tgt & (N2_ - 1);
            float y = 0.f;
            for (int s2 = 0; s2 < 32; ++s2)
                y += p.pb[((size_t)s2 * B_ + b) * N2_ + k];
            float V = __fadd_rn(__fmul_rn(0.9f, p.V2[tgt]), y);
            float rr = p.r2[tgt];
            bool spk = (V > 1.0f) && (rr <= 0.0f);
            float s = spk ? 1.0f : 0.0f;
            p.V2[tgt] = spk ? 0.0f : V;
            p.r2[tgt] = spk ? 2.0f : fmaxf(rr - 1.0f, 0.0f);
            p.s2bk[((size_t)dc * B_ + b) * N2_ + k] = s;
            p.q1bk[((size_t)dc * B_ + b) * N2_ + k] =
                __fadd_rn(__fmul_rn(0.95f, p.q1bk[((size_t)dp * B_ + b) * N2_ + k]), s);
            p.counts[tgt] += s;
        }

        // ---- phase A: Wa update (traces t-1) + partial y1 = s0(t) @ Wa ----
        {
            const int jt = bx & 15, isup = bx >> 4;
            const int i0 = isup * 256 + iq * 64;
            const int j  = jt * 256 + jq * 64 + lane;
            const float* s0t = p.s0 + (size_t)t * ((size_t)N0_ * B_);
            float acc[16];
            #pragma unroll
            for (int b = 0; b < 16; ++b) acc[b] = 0.f;

            if (t > 0) {
                {   // stage p0(t-1), s0(t-1) rows for this block's 256 i
                    int row = tix >> 2, pt4 = tix & 3;
                    size_t base = ((size_t)(t - 1) * N0_ + isup * 256 + row) * B_;
                    float4 a = ((const float4*)(p.p0 + base))[pt4];
                    float4 c = ((const float4*)(p.s0 + base))[pt4];
                    ((float4*)trA)[row * 4 + pt4] = a;
                    ((float4*)trA)[1024 + row * 4 + pt4] = c;
                }
                float s1v[16], q0v[16];
                #pragma unroll
                for (int b = 0; b < 16; ++b) {
                    s1v[b] = p.s1bj[((size_t)prv * B_ + b) * N1_ + j];
                    q0v[b] = p.q0bj[((size_t)prv * B_ + b) * N1_ + j];
                }
                __syncthreads();
                float wc[4], wn[4];
                #pragma unroll
                for (int k = 0; k < 4; ++k) wc[k] = p.Wa[(size_t)(i0 + k) * N1_ + j];
                for (int g = 0; g < 16; ++g) {
                    if (g < 15) {
                        #pragma unroll
                        for (int k = 0; k < 4; ++k)
                            wn[k] = p.Wa[(size_t)(i0 + g * 4 + 4 + k) * N1_ + j];
                    }
                    #pragma unroll
                    for (int k = 0; k < 4; ++k) {
                        int ib = g * 4 + k;
                        int ilds = iq * 64 + ib;
                        const float4* pr = (const float4*)trA + ilds * 4;
                        const float4* sr = (const float4*)trA + 1024 + ilds * 4;
                        float4 p0a = pr[0], p0b = pr[1], p0c = pr[2], p0d = pr[3];
                        float4 s0a = sr[0], s0b = sr[1], s0c = sr[2], s0d = sr[3];
                        const float4* sc = (const float4*)(s0t + (size_t)(i0 + ib) * B_);
                        float4 c0 = sc[0], c1 = sc[1], c2 = sc[2], c3 = sc[3];
                        float t1 = dot16q(p0a, p0b, p0c, p0d, s1v);
                        float t2 = dot16q(s0a, s0b, s0c, s0d, q0v);
                        float wv = __fadd_rn(wc[k], __fmul_rn(0.01f, __fsub_rn(t1, t2)));
                        wv = fminf(fmaxf(wv, -1.0f), 1.0f);
                        if (sw) p.Wa[(size_t)(i0 + ib) * N1_ + j] = wv;
                        acc16q(acc, c0, c1, c2, c3, wv);
                    }
                    #pragma unroll
                    for (int k = 0; k < 4; ++k) wc[k] = wn[k];
                }
            } else {
                for (int g = 0; g < 16; ++g) {
                    #pragma unroll
                    for (int k = 0; k < 4; ++k) {
                        int ib = g * 4 + k;
                        float wv = p.Wa[(size_t)(i0 + ib) * N1_ + j];
                        const float4* sc = (const float4*)(s0t + (size_t)(i0 + ib) * B_);
                        acc16q(acc, sc[0], sc[1], sc[2], sc[3], wv);
                    }
                }
            }
            // deterministic in-block reduce over iq (ascending rounds)
            for (int r = 0; r < 4; ++r) {
                if (iq == r) {
                    #pragma unroll
                    for (int b = 0; b < 16; ++b) {
                        int idx = b * 256 + jq * 64 + lane;
                        part2[idx] = (r == 0) ? acc[b] : __fadd_rn(part2[idx], acc[b]);
                    }
                }
                __syncthreads();
            }
            #pragma unroll
            for (int k2 = 0; k2 < 4; ++k2) {
                int tgt = k2 * 1024 + tix;
                int b = tgt >> 8, j256 = tgt & 255;
                p.pa[((size_t)isup * B_ + b) * N1_ + jt * 256 + j256] = part2[tgt];
            }
        }
        gbar(p.bar, p.bar + 1, mygen);

        // ---- phase B: lif1 ----
        if (tix < 256) {
            int tgt = bx * 256 + tix;                  // 65536 = B*N1
            int b = tgt >> 12, jc = tgt & (N1_ - 1);
            float y = 0.f;
            for (int s2 = 0; s2 < 16; ++s2)
                y += p.pa[((size_t)s2 * B_ + b) * N1_ + jc];
            float V = __fadd_rn(__fmul_rn(0.9f, p.V1[tgt]), y);
            float rr = p.r1[tgt];
            bool spk = (V > 1.0f) && (rr <= 0.0f);
            float s = spk ? 1.0f : 0.0f;
            p.V1[tgt] = spk ? 0.0f : V;
            p.r1[tgt] = spk ? 2.0f : fmaxf(rr - 1.0f, 0.0f);
            p.s1bj[((size_t)cur * B_ + b) * N1_ + jc] = s;
            p.s1r[((size_t)cur * N1_ + jc) * B_ + b] = s;
            p.q0bj[((size_t)cur * B_ + b) * N1_ + jc] =
                __fadd_rn(__fmul_rn(0.95f, p.q0bj[((size_t)prv * B_ + b) * N1_ + jc]), s);
            p.p1r[((size_t)cur * N1_ + jc) * B_ + b] =
                __fadd_rn(__fmul_rn(0.95f, p.p1r[((size_t)prv * N1_ + jc) * B_ + b]), s);
        }
        gbar(p.bar, p.bar + 1, mygen);

        // ---- phase C: Wb update (traces t-1) + partial y2 = s1(t) @ Wb ----
        {
            const int jt2 = bx & 7, isup2 = bx >> 3;
            const int i0 = isup2 * 128 + iq * 32;
            const int j  = jt2 * 256 + jq * 64 + lane;
            const float* s1c = p.s1r + (size_t)cur * N1_ * B_;
            float acc[16];
            #pragma unroll
            for (int b = 0; b < 16; ++b) acc[b] = 0.f;

            if (t > 0) {
                {   // stage p1(t-1), s1(t-1) rows (128 each)
                    int arr = tix >> 9, row = (tix >> 2) & 127, pt4 = tix & 3;
                    const float* src = (arr == 0)
                        ? (p.p1r + ((size_t)prv * N1_ + isup2 * 128 + row) * B_)
                        : (p.s1r + ((size_t)prv * N1_ + isup2 * 128 + row) * B_);
                    float4 a = ((const float4*)src)[pt4];
                    ((float4*)trA)[arr * 512 + row * 4 + pt4] = a;
                }
                float s2v[16], q1v[16];
                #pragma unroll
                for (int b = 0; b < 16; ++b) {
                    s2v[b] = p.s2bk[((size_t)prv * B_ + b) * N2_ + j];
                    q1v[b] = p.q1bk[((size_t)prv * B_ + b) * N2_ + j];
                }
                __syncthreads();
                float wc[4], wn[4];
                #pragma unroll
                for (int k = 0; k < 4; ++k) wc[k] = p.Wb[(size_t)(i0 + k) * N2_ + j];
                for (int g = 0; g < 8; ++g) {
                    if (g < 7) {
                        #pragma unroll
                        for (int k = 0; k < 4; ++k)
                            wn[k] = p.Wb[(size_t)(i0 + g * 4 + 4 + k) * N2_ + j];
                    }
                    #pragma unroll
                    for (int k = 0; k < 4; ++k) {
                        int ib = g * 4 + k;
                        int ilds = iq * 32 + ib;
                        const float4* pr = (const float4*)trA + ilds * 4;
                        const float4* sr = (const float4*)trA + 512 + ilds * 4;
                        float4 p1a = pr[0], p1b = pr[1], p1c = pr[2], p1d = pr[3];
                        float4 s1a = sr[0], s1b = sr[1], s1cc = sr[2], s1d = sr[3];
                        const float4* sc = (const float4*)(s1c + (size_t)(i0 + ib) * B_);
                        float4 c0 = sc[0], c1 = sc[1], c2 = sc[2], c3 = sc[3];
                        float t1 = dot16q(p1a, p1b, p1c, p1d, s2v);
                        float t2 = dot16q(s1a, s1b, s1cc, s1d, q1v);
                        float wv = __fadd_rn(wc[k], __fmul_rn(0.01f, __fsub_rn(t1, t2)));
                        wv = fminf(fmaxf(wv, -1.0f), 1.0f);
                        if (sw) p.Wb[(size_t)(i0 + ib) * N2_ + j] = wv;
                        acc16q(acc, c0, c1, c2, c3, wv);
                    }
                    #pragma unroll
                    for (int k = 0; k < 4; ++k) wc[k] = wn[k];
                }
            } else {
                for (int g = 0; g < 8; ++g) {
                    #pragma unroll
                    for (int k = 0; k < 4; ++k) {
                        int ib = g * 4 + k;
                        float wv = p.Wb[(size_t)(i0 + ib) * N2_ + j];
                        const float4* sc = (const float4*)(s1c + (size_t)(i0 + ib) * B_);
                        acc16q(acc, sc[0], sc[1], sc[2], sc[3], wv);
                    }
                }
            }
            for (int r = 0; r < 4; ++r) {
                if (iq == r) {
                    #pragma unroll
                    for (int b = 0; b < 16; ++b) {
                        int idx = b * 256 + jq * 64 + lane;
                        part2[idx] = (r == 0) ? acc[b] : __fadd_rn(part2[idx], acc[b]);
                    }
                }
                __syncthreads();
            }
            #pragma unroll
            for (int k2 = 0; k2 < 4; ++k2) {
                int tgt = k2 * 1024 + tix;
                int b = tgt >> 8, j256 = tgt & 255;
                p.pb[((size_t)isup2 * B_ + b) * N2_ + jt2 * 256 + j256] = part2[tgt];
            }
        }
        gbar(p.bar, p.bar + 1, mygen);
    }

    // final lif2 for t = T-1
    if (tix < 128) {
        int td = T_ - 1, dc = td & 1;
        int tgt = bx * 128 + tix;
        int b = tgt >> 11, k = tgt & (N2_ - 1);
        float y = 0.f;
        for (int s2 = 0; s2 < 32; ++s2)
            y += p.pb[((size_t)s2 * B_ + b) * N2_ + k];
        float V = __fadd_rn(__fmul_rn(0.9f, p.V2[tgt]), y);
        float rr = p.r2[tgt];
        bool spk = (V > 1.0f) && (rr <= 0.0f);
        float s = spk ? 1.0f : 0.0f;
        (void)dc;
        p.counts[tgt] += s;
    }
    gbar(p.bar, p.bar + 1, mygen);

    // decode
    if (bx == 0 && tix < B_ * NC_) {
        int b = tix / NC_, c = tix % NC_;
        float a = 0.f;
        for (int k = 0; k < N2_; ++k)
            a = fmaf(p.counts[(size_t)b * N2_ + k], p.Wdec[(size_t)k * NC_ + c], a);
        p.out[tix] = __fadd_rn(a, p.bdec[c]);
    }
}

extern "C" void kernel_launch(void* const* d_in, const int* in_sizes, int n_in,
                              void* d_out, int out_size, void* d_ws, size_t ws_size,
                              hipStream_t stream) {
    const float* x     = (const float*)d_in[0];
    const float* u     = (const float*)d_in[1];
    const float* W_enc = (const float*)d_in[2];
    const float* b_enc = (const float*)d_in[3];
    float* Wa          = (float*)d_in[4];   // in-place; harness restores each launch
    float* Wb          = (float*)d_in[5];
    const float* W_dec = (const float*)d_in[6];
    const float* b_dec = (const float*)d_in[7];

    float* ws = (float*)d_ws;
    size_t off = 0;
    float* rates  = ws + off; off += (size_t)B_ * N0_;
    float* s0_all = ws + off; off += (size_t)T_ * N0_ * B_;
    float* p0_all = ws + off; off += (size_t)T_ * N0_ * B_;
    float* s1_bj  = ws + off; off += 2 * (size_t)B_ * N1_;
    float* pa     = ws + off; off += 16 * (size_t)B_ * N1_;
    float* pb     = ws + off; off += 32 * (size_t)B_ * N2_;
    float* zblock = ws + off;                       // zero-init below
    float* barp   = ws + off; off += 4;             // 2 unsigned barrier words
    float* q0_bj  = ws + off; off += 2 * (size_t)B_ * N1_;
    float* s1_r   = ws + off; off += 2 * (size_t)B_ * N1_;
    float* p1_r   = ws + off; off += 2 * (size_t)B_ * N1_;
    float* q1_bk  = ws + off; off += 2 * (size_t)B_ * N2_;
    float* s2_bk  = ws + off; off += 2 * (size_t)B_ * N2_;
    float* V1     = ws + off; off += (size_t)B_ * N1_;
    float* r1     = ws + off; off += (size_t)B_ * N1_;
    float* V2     = ws + off; off += (size_t)B_ * N2_;
    float* r2     = ws + off; off += (size_t)B_ * N2_;
    float* counts = ws + off; off += (size_t)B_ * N2_;
    size_t zbytes = (size_t)((ws + off) - zblock) * sizeof(float);

    hipMemsetAsync(zblock, 0, zbytes, stream);
    rates_kernel<<<256, 256, 0, stream>>>(x, W_enc, b_enc, rates);
    layer0_kernel<<<256, 256, 0, stream>>>(u, rates, s0_all, p0_all);

    Ptrs p;
    p.Wa = Wa; p.Wb = Wb;
    p.s0 = s0_all; p.p0 = p0_all;
    p.Wdec = W_dec; p.bdec = b_dec;
    p.out = (float*)d_out;
    p.s1bj = s1_bj; p.s1r = s1_r; p.q0bj = q0_bj; p.p1r = p1_r;
    p.s2bk = s2_bk; p.q1bk = q1_bk;
    p.pa = pa; p.pb = pb;
    p.V1 = V1; p.r1 = r1; p.V2 = V2; p.r2 = r2;
    p.counts = counts;
    p.bar = (unsigned*)barp;

    snn_kernel<<<NBLK_, NTHR_, 0, stream>>>(p);
}

// Round 5
// 58353.003 us; speedup vs baseline: 1.8218x; 1.8218x over previous
//
#include <hip/hip_runtime.h>
#include <math.h>

#define B_  16
#define D_  2048
#define T_  100
#define N0_ 4096
#define N1_ 4096
#define N2_ 2048
#define NC_ 10
#define NBLK_ 256
#define NTHR_ 512
#define RSTR_ 20   // padded LDS reduce row stride (floats)

struct P {
    const float* Wa;                    // (N0, N1) original, read-only (resident copy in regs)
    const float* Wdec; const float* bdec;
    const float* s0; const float* p0;   // (T, N0, B)
    float* Wbp;                         // (256, 4096, 8) permuted Wb, streamed + updated
    float* s1r; float* p1r;             // (3, N1, B) triple-buffered trace rows
    float* counts;                      // (B, N2)
    float* out;
    unsigned* bar;                      // [cnt, gen]
};

// ---------------- rates = sigmoid(x @ W_enc + b_enc) ----------------
__global__ __launch_bounds__(256) void rates_kernel(
    const float* __restrict__ x, const float* __restrict__ W_enc,
    const float* __restrict__ b_enc, float* __restrict__ rates)
{
    int tid = blockIdx.x * 256 + threadIdx.x;      // 65536 = B*N0
    int b = tid >> 12, i = tid & (N0_ - 1);
    const float* xr = x + b * D_;
    float acc = 0.f;
    for (int d = 0; d < D_; ++d)
        acc = fmaf(xr[d], W_enc[(size_t)d * N0_ + i], acc);
    float z = __fadd_rn(acc, b_enc[i]);
    rates[tid] = 1.0f / (1.0f + expf(-z));
}

// ---- layer-0 LIF over all T (weight-independent): s0, p0 in (T,N0,B) ----
__global__ __launch_bounds__(256) void layer0_kernel(
    const float* __restrict__ u, const float* __restrict__ rates,
    float* __restrict__ s0_all, float* __restrict__ p0_all)
{
    int tid = blockIdx.x * 256 + threadIdx.x;      // 65536
    int b = tid & (B_ - 1), i = tid >> 4;
    float rate = rates[b * N0_ + i];
    const float* ub = u + (size_t)b * T_ * N0_ + i;
    float V = 0.f, refr = 0.f, p0 = 0.f;
    for (int t = 0; t < T_; ++t) {
        float uv = ub[(size_t)t * N0_];
        float s_in = (uv < rate) ? 1.0f : 0.0f;
        V = __fadd_rn(__fmul_rn(0.9f, V), s_in);
        bool spk = (V > 1.0f) && (refr <= 0.0f);
        float s = spk ? 1.0f : 0.0f;
        V = spk ? 0.0f : V;
        refr = spk ? 2.0f : fmaxf(refr - 1.0f, 0.0f);
        p0 = __fadd_rn(__fmul_rn(0.95f, p0), s);
        size_t idx = ((size_t)t * N0_ + i) * B_ + b;
        s0_all[idx] = s;
        p0_all[idx] = p0;
    }
}

// ---- permute Wb (N1,N2) -> Wbp[c][j][k] so each block's slice is contiguous ----
__global__ __launch_bounds__(256) void wbperm_kernel(
    const float* __restrict__ Wb, float* __restrict__ Wbp)
{
    int tid = blockIdx.x * 256 + threadIdx.x;      // 8388608
    int j = tid >> 11, kk = tid & (N2_ - 1);
    int c = kk >> 3, k = kk & 7;
    Wbp[((size_t)c * N1_ + j) * 8 + k] = Wb[tid];
}

__device__ __forceinline__ float dot16q(float4 a0, float4 a1, float4 a2, float4 a3,
                                        const float* v) {
    float t = 0.f;
    t = fmaf(a0.x, v[0], t);  t = fmaf(a0.y, v[1], t);
    t = fmaf(a0.z, v[2], t);  t = fmaf(a0.w, v[3], t);
    t = fmaf(a1.x, v[4], t);  t = fmaf(a1.y, v[5], t);
    t = fmaf(a1.z, v[6], t);  t = fmaf(a1.w, v[7], t);
    t = fmaf(a2.x, v[8], t);  t = fmaf(a2.y, v[9], t);
    t = fmaf(a2.z, v[10], t); t = fmaf(a2.w, v[11], t);
    t = fmaf(a3.x, v[12], t); t = fmaf(a3.y, v[13], t);
    t = fmaf(a3.z, v[14], t); t = fmaf(a3.w, v[15], t);
    return t;
}
__device__ __forceinline__ void acc16q(float* acc, float4 a0, float4 a1, float4 a2,
                                       float4 a3, float w) {
    acc[0]  = fmaf(a0.x, w, acc[0]);  acc[1]  = fmaf(a0.y, w, acc[1]);
    acc[2]  = fmaf(a0.z, w, acc[2]);  acc[3]  = fmaf(a0.w, w, acc[3]);
    acc[4]  = fmaf(a1.x, w, acc[4]);  acc[5]  = fmaf(a1.y, w, acc[5]);
    acc[6]  = fmaf(a1.z, w, acc[6]);  acc[7]  = fmaf(a1.w, w, acc[7]);
    acc[8]  = fmaf(a2.x, w, acc[8]);  acc[9]  = fmaf(a2.y, w, acc[9]);
    acc[10] = fmaf(a2.z, w, acc[10]); acc[11] = fmaf(a2.w, w, acc[11]);
    acc[12] = fmaf(a3.x, w, acc[12]); acc[13] = fmaf(a3.y, w, acc[13]);
    acc[14] = fmaf(a3.z, w, acc[14]); acc[15] = fmaf(a3.w, w, acc[15]);
}

// Grid barrier: RELAXED polls (no per-poll cache invalidate), one full fence each side.
// Co-residency: 256 blocks x 8 waves, VGPR<=256 & LDS<64KB -> >=1 block/CU on 256 CUs.
__device__ __forceinline__ void gbar(unsigned* cnt, unsigned* gen, unsigned target) {
    __threadfence();            // release: wb dirty L2 (small: spike rows + Wb slice)
    __syncthreads();
    if (threadIdx.x == 0) {
        unsigned v = __hip_atomic_fetch_add(cnt, 1u, __ATOMIC_RELAXED,
                                            __HIP_MEMORY_SCOPE_AGENT);
        if (v == NBLK_ - 1u) {
            __hip_atomic_store(cnt, 0u, __ATOMIC_RELAXED, __HIP_MEMORY_SCOPE_AGENT);
            __hip_atomic_store(gen, target, __ATOMIC_RELAXED, __HIP_MEMORY_SCOPE_AGENT);
        } else {
            while (__hip_atomic_load(gen, __ATOMIC_RELAXED,
                                     __HIP_MEMORY_SCOPE_AGENT) < target)
                __builtin_amdgcn_s_sleep(4);
        }
    }
    __syncthreads();
    __threadfence();            // acquire side: invalidate so peers' rows are visible
}

__global__ __launch_bounds__(NTHR_, 2) void snn_kernel(P p)
{
    __shared__ float red[16 * 16 * RSTR_];             // 20 KB, reused by phase C
    __shared__ float s1loc[256], q0loc[256], V1loc[256], r1loc[256];
    __shared__ float s2loc[128], q1loc[128], V2loc[128], r2loc[128], cnt[128];
    const int tix = threadIdx.x, bx = blockIdx.x;

    if (tix < 256) {
        s1loc[tix] = 0.f; q0loc[tix] = 0.f; V1loc[tix] = 0.f; r1loc[tix] = 0.f;
        if (tix < 128) {
            s2loc[tix] = 0.f; q1loc[tix] = 0.f; V2loc[tix] = 0.f; r2loc[tix] = 0.f;
            cnt[tix] = 0.f;
        }
    }

    // ---- resident Wa slice: columns [16bx, 16bx+16), thread (jA, gA) owns i = gA+32*ii
    const int jA = tix & 15, gA = tix >> 4;
    const int jglob = bx * 16 + jA;
    float wa[128];
    #pragma unroll
    for (int ii = 0; ii < 128; ++ii)
        wa[ii] = p.Wa[(size_t)(gA + (ii << 5)) * N1_ + jglob];

    const int kC = tix & 7, GC = tix >> 3;
    float* wbbase = p.Wbp + (size_t)bx * N1_ * 8;
    __syncthreads();

    unsigned tgt = 0;
    for (int t = 0; t < T_; ++t) {
        const int ws_ = t % 3, ps_ = (t + 2) % 3;      // write slot / t-1 slot
        const int tp = (t > 0) ? (t - 1) : 0;          // t=0: dots are *0 anyway

        // ================= phase A: Wa update (t-1) + y1 = s0(t) @ Wa =================
        float s1v[16], q0v[16], acc[16];
        #pragma unroll
        for (int b = 0; b < 16; ++b) {
            s1v[b] = s1loc[jA * 16 + b];               // s1(t-1), zeros at t=0
            q0v[b] = q0loc[jA * 16 + b];               // q0(t-1)
            acc[b] = 0.f;
        }
        {
            const float* s0t = p.s0 + (size_t)t  * N0_ * B_;
            const float* s0p = p.s0 + (size_t)tp * N0_ * B_;
            const float* p0p = p.p0 + (size_t)tp * N0_ * B_;
            #pragma unroll
            for (int ii = 0; ii < 128; ++ii) {
                const int i = gA + (ii << 5);
                const float4* ap = (const float4*)(p0p + (size_t)i * B_);
                const float4* bp = (const float4*)(s0p + (size_t)i * B_);
                const float4* cp = (const float4*)(s0t + (size_t)i * B_);
                float4 a0 = ap[0], a1 = ap[1], a2 = ap[2], a3 = ap[3];
                float4 b0 = bp[0], b1 = bp[1], b2 = bp[2], b3 = bp[3];
                float4 c0 = cp[0], c1 = cp[1], c2 = cp[2], c3 = cp[3];
                float t1 = dot16q(a0, a1, a2, a3, s1v);
                float t2 = dot16q(b0, b1, b2, b3, q0v);
                float wv = __fadd_rn(wa[ii], __fmul_rn(0.01f, __fsub_rn(t1, t2)));
                wv = fminf(fmaxf(wv, -1.0f), 1.0f);    // t=0: no-op (|w|<1 whp)
                wa[ii] = wv;
                acc16q(acc, c0, c1, c2, c3, wv);
            }
        }
        // fixed-order in-block reduce over gA (slot s gets g=s then g=s+16)
        {
            float* rp = &red[((gA & 15) * 16 + jA) * RSTR_];
            if (gA < 16) {
                #pragma unroll
                for (int q = 0; q < 4; ++q)
                    ((float4*)rp)[q] = make_float4(acc[4*q], acc[4*q+1], acc[4*q+2], acc[4*q+3]);
            }
            __syncthreads();
            if (gA >= 16) {
                #pragma unroll
                for (int b = 0; b < 16; ++b) rp[b] = __fadd_rn(rp[b], acc[b]);
            }
            __syncthreads();
        }
        // lif1 for this block's 16 j (local state), publish s1/p1 rows globally
        if (tix < 256) {
            int j = tix >> 4, b = tix & 15, idx = j * 16 + b;
            float y = 0.f;
            #pragma unroll
            for (int s = 0; s < 16; ++s) y = __fadd_rn(y, red[(s * 16 + j) * RSTR_ + b]);
            float V = __fadd_rn(__fmul_rn(0.9f, V1loc[idx]), y);
            float rr = r1loc[idx];
            bool spk = (V > 1.0f) && (rr <= 0.0f);
            float s = spk ? 1.0f : 0.0f;
            V1loc[idx] = spk ? 0.0f : V;
            r1loc[idx] = spk ? 2.0f : fmaxf(rr - 1.0f, 0.0f);
            s1loc[idx] = s;
            q0loc[idx] = __fadd_rn(__fmul_rn(0.95f, q0loc[idx]), s);
            int jg = bx * 16 + j;
            p.s1r[((size_t)ws_ * N1_ + jg) * B_ + b] = s;
            float p1o = p.p1r[((size_t)ps_ * N1_ + jg) * B_ + b];
            p.p1r[((size_t)ws_ * N1_ + jg) * B_ + b] = __fadd_rn(__fmul_rn(0.95f, p1o), s);
        }
        gbar(p.bar, p.bar + 1, ++tgt);

        // ================= phase C: Wb update (t-1) + y2 = s1(t) @ Wb =================
        float s2v[16], q1v[16], ac2[16];
        #pragma unroll
        for (int b = 0; b < 16; ++b) {
            s2v[b] = s2loc[kC * 16 + b];               // s2(t-1)
            q1v[b] = q1loc[kC * 16 + b];               // q1(t-1)
            ac2[b] = 0.f;
        }
        {
            const float* s1c = p.s1r + (size_t)ws_ * N1_ * B_;
            const float* s1p = p.s1r + (size_t)ps_ * N1_ * B_;
            const float* p1p = p.p1r + (size_t)ps_ * N1_ * B_;
            float wv = wbbase[(size_t)GC * 8 + kC];
            #pragma unroll 2
            for (int jj = 0; jj < 64; ++jj) {
                const int j = GC + (jj << 6);
                float wnx = (jj < 63) ? wbbase[(size_t)(j + 64) * 8 + kC] : 0.f;
                const float4* ap = (const float4*)(p1p + (size_t)j * B_);
                const float4* bp = (const float4*)(s1p + (size_t)j * B_);
                const float4* cp = (const float4*)(s1c + (size_t)j * B_);
                float4 a0 = ap[0], a1 = ap[1], a2 = ap[2], a3 = ap[3];
                float4 b0 = bp[0], b1 = bp[1], b2 = bp[2], b3 = bp[3];
                float4 c0 = cp[0], c1 = cp[1], c2 = cp[2], c3 = cp[3];
                float t1 = dot16q(a0, a1, a2, a3, s2v);
                float t2 = dot16q(b0, b1, b2, b3, q1v);
                float wn = __fadd_rn(wv, __fmul_rn(0.01f, __fsub_rn(t1, t2)));
                wn = fminf(fmaxf(wn, -1.0f), 1.0f);
                wbbase[(size_t)j * 8 + kC] = wn;
                acc16q(ac2, c0, c1, c2, c3, wn);
                wv = wnx;
            }
        }
        // fixed-order reduce over GC (slot s gets G=s then G=s+32), then lif2
        {
            float* rp = &red[((GC & 31) * 8 + kC) * RSTR_];
            if (GC < 32) {
                #pragma unroll
                for (int q = 0; q < 4; ++q)
                    ((float4*)rp)[q] = make_float4(ac2[4*q], ac2[4*q+1], ac2[4*q+2], ac2[4*q+3]);
            }
            __syncthreads();
            if (GC >= 32) {
                #pragma unroll
                for (int b = 0; b < 16; ++b) rp[b] = __fadd_rn(rp[b], ac2[b]);
            }
            __syncthreads();
        }
        if (tix < 128) {
            int k = tix >> 4, b = tix & 15, idx = k * 16 + b;
            float y = 0.f;
            #pragma unroll
            for (int s = 0; s < 32; ++s) y = __fadd_rn(y, red[(s * 8 + k) * RSTR_ + b]);
            float V = __fadd_rn(__fmul_rn(0.9f, V2loc[idx]), y);
            float rr = r2loc[idx];
            bool spk = (V > 1.0f) && (rr <= 0.0f);
            float s = spk ? 1.0f : 0.0f;
            V2loc[idx] = spk ? 0.0f : V;
            r2loc[idx] = spk ? 2.0f : fmaxf(rr - 1.0f, 0.0f);
            s2loc[idx] = s;
            q1loc[idx] = __fadd_rn(__fmul_rn(0.95f, q1loc[idx]), s);
            cnt[idx] = cnt[idx] + s;
        }
        gbar(p.bar, p.bar + 1, ++tgt);
    }

    // publish counts, final barrier, decode by block 0
    if (tix < 128) {
        int k = tix >> 4, b = tix & 15;
        p.counts[(size_t)b * N2_ + bx * 8 + k] = cnt[k * 16 + b];
    }
    gbar(p.bar, p.bar + 1, ++tgt);
    if (bx == 0 && tix < B_ * NC_) {
        int b = tix / NC_, c = tix % NC_;
        float a = 0.f;
        for (int k = 0; k < N2_; ++k)
            a = fmaf(p.counts[(size_t)b * N2_ + k], p.Wdec[(size_t)k * NC_ + c], a);
        p.out[tix] = __fadd_rn(a, p.bdec[c]);
    }
}

extern "C" void kernel_launch(void* const* d_in, const int* in_sizes, int n_in,
                              void* d_out, int out_size, void* d_ws, size_t ws_size,
                              hipStream_t stream) {
    (void)in_sizes; (void)n_in; (void)out_size; (void)ws_size;
    const float* x     = (const float*)d_in[0];
    const float* u     = (const float*)d_in[1];
    const float* W_enc = (const float*)d_in[2];
    const float* b_enc = (const float*)d_in[3];
    const float* Wa    = (const float*)d_in[4];   // never written (resident in regs)
    const float* Wb    = (const float*)d_in[5];   // never written (permuted copy in ws)
    const float* W_dec = (const float*)d_in[6];
    const float* b_dec = (const float*)d_in[7];

    float* ws = (float*)d_ws;
    size_t off = 0;
    float* rates  = ws + off; off += (size_t)B_ * N0_;
    float* s0_all = ws + off; off += (size_t)T_ * N0_ * B_;
    float* p0_all = ws + off; off += (size_t)T_ * N0_ * B_;
    float* Wbp    = ws + off; off += (size_t)N1_ * N2_;
    float* counts = ws + off; off += (size_t)B_ * N2_;
    float* zblock = ws + off;                       // zero-init below
    float* s1r    = ws + off; off += 3 * (size_t)N1_ * B_;
    float* p1r    = ws + off; off += 3 * (size_t)N1_ * B_;
    float* barp   = ws + off; off += 16;
    size_t zbytes = (size_t)((ws + off) - zblock) * sizeof(float);

    hipMemsetAsync(zblock, 0, zbytes, stream);
    rates_kernel<<<256, 256, 0, stream>>>(x, W_enc, b_enc, rates);
    layer0_kernel<<<256, 256, 0, stream>>>(u, rates, s0_all, p0_all);
    wbperm_kernel<<<(N1_ * N2_) / 256, 256, 0, stream>>>(Wb, Wbp);

    P p;
    p.Wa = Wa; p.Wdec = W_dec; p.bdec = b_dec;
    p.s0 = s0_all; p.p0 = p0_all;
    p.Wbp = Wbp; p.s1r = s1r; p.p1r = p1r;
    p.counts = counts; p.out = (float*)d_out;
    p.bar = (unsigned*)barp;

    snn_kernel<<<NBLK_, NTHR_, 0, stream>>>(p);
}